// Round 6
// baseline (790.320 us; speedup 1.0000x reference)
//
#include <hip/hip_runtime.h>
#include <hip/hip_bf16.h>
#include <cstdint>

// ---------------------------------------------------------------------------
// LSTM cell fused forward on MI355X (gfx950).
//   gates = [input|hidden] @ [W;U] + b   (fp32 via 3-product bf16 MFMA emulation)
//   gate GEMM: 256x128 tile, 32x32x16 MFMA, panel-linear LDS (conflict-free),
//              TRIPLE-buffered, 1 barrier/K-tile, counted lgkmcnt clusters
//              overlapping LDS port with MFMA pipe, counted vmcnt(6)
//   elementwise LSTM epilogue fused into gate GEMM
//   logits = h_new @ W_h + b_h           (128^2 bf16x3 GEMM)
//   log_softmax row-wise
// ---------------------------------------------------------------------------

#define B_DIM   8192
#define K1      2048   // IN + H
#define H_DIM   1024

typedef __attribute__((ext_vector_type(8)))  __bf16 bf16x8;
typedef __attribute__((ext_vector_type(4)))  float  f32x4;
typedef __attribute__((ext_vector_type(16))) float  f32x16;
typedef __attribute__((ext_vector_type(8)))  unsigned short u16x8;

__device__ __forceinline__ unsigned short f2bf(float f) {
    unsigned int u = __float_as_uint(f);
    u += 0x7FFFu + ((u >> 16) & 1u);
    return (unsigned short)(u >> 16);
}
__device__ __forceinline__ float bf2f(unsigned short s) {
    return __uint_as_float(((unsigned int)s) << 16);
}

__device__ __forceinline__ void gload_lds16(const void* g, void* l) {
    __builtin_amdgcn_global_load_lds(
        (const __attribute__((address_space(1))) void*)g,
        (__attribute__((address_space(3))) void*)l, 16, 0, 0);
}

__device__ __forceinline__ unsigned lds_off(const void* p) {
    return (unsigned)(uintptr_t)(const __attribute__((address_space(3))) void*)p;
}

// ds_read_b128 with immediate offset; asm keeps it out of the legalizer's way
#define DSR(dst, base, off)                                                  \
    asm volatile("ds_read_b128 %0, %1 offset:" #off : "=v"(dst) : "v"(base))

__device__ __forceinline__ f32x4 mfma16(bf16x8 a, bf16x8 b, f32x4 c) {
    return __builtin_amdgcn_mfma_f32_16x16x32_bf16(a, b, c, 0, 0, 0);
}
__device__ __forceinline__ f32x16 mfma32(bf16x8 a, bf16x8 b, f32x16 c) {
    return __builtin_amdgcn_mfma_f32_32x32x16_bf16(a, b, c, 0, 0, 0);
}

#define SCHED0() __builtin_amdgcn_sched_barrier(0)

// A panel layout (256-row panels, K=2048): element (r,k), part p:
//   byte = ((panel*64 + t)*32 + g*4 + kk*2 + p)*1024 + (lh*32+l31)*16 + j*2
//   panel=r>>8 g=(r>>5)&7 l31=r&31 t=k>>5 kk=(k>>4)&1 lh=(k>>3)&1 j=k&7
__device__ __forceinline__ int64_t pan_addr_a(int r, int k) {
    int panel = r >> 8, g = (r >> 5) & 7, l31 = r & 31;
    int t = k >> 5, kk = (k >> 4) & 1, lh = (k >> 3) & 1, j = k & 7;
    return ((int64_t)((panel * 64 + t) * 32 + g * 4 + kk * 2)) * 1024
           + (lh * 32 + l31) * 16 + j * 2;
}
// B panel layout (128-row panels, K=2048): 16 KB per tile per panel
__device__ __forceinline__ int64_t pan_addr_b(int np, int k) {
    int panel = np >> 7, g = (np >> 5) & 3, l31 = np & 31;
    int t = k >> 5, kk = (k >> 4) & 1, lh = (k >> 3) & 1, j = k & 7;
    return ((int64_t)((panel * 64 + t) * 16 + g * 4 + kk * 2)) * 1024
           + (lh * 32 + l31) * 16 + j * 2;
}

// ---------------------------------------------------------------------------
// Pack X = [input | hidden] into A panel layout, 16B granule stores.
// ---------------------------------------------------------------------------
__global__ __launch_bounds__(256) void k_pack_x(
    const float* __restrict__ input, const float* __restrict__ hidden,
    char* __restrict__ Apan) {
    const int64_t n8 = (int64_t)B_DIM * K1 / 8;
    for (int64_t i = (int64_t)blockIdx.x * blockDim.x + threadIdx.x; i < n8;
         i += (int64_t)gridDim.x * blockDim.x) {
        int64_t e = i * 8;
        int row = (int)(e >> 11);
        int col = (int)(e & 2047);
        const float* src = (col < 1024) ? (input + (int64_t)row * 1024 + col)
                                        : (hidden + (int64_t)row * 1024 + (col - 1024));
        float4 v0 = *(const float4*)src;
        float4 v1 = *(const float4*)(src + 4);
        u16x8 hv, lv;
        float vv[8] = {v0.x, v0.y, v0.z, v0.w, v1.x, v1.y, v1.z, v1.w};
        #pragma unroll
        for (int j = 0; j < 8; j++) {
            unsigned short hi = f2bf(vv[j]);
            hv[j] = hi;
            lv[j] = f2bf(vv[j] - bf2f(hi));
        }
        int64_t a = pan_addr_a(row, col);  // col%8==0 -> 16B aligned
        *(u16x8*)(Apan + a) = hv;
        *(u16x8*)(Apan + a + 1024) = lv;
    }
}

// ---------------------------------------------------------------------------
// Transpose+split W/U [1024x1024] into B panel layout at n'=4h+ng, k=koff+kl.
// 16B granule stores.
// ---------------------------------------------------------------------------
__global__ __launch_bounds__(256) void k_trans_split_pan(
    const float* __restrict__ src, char* __restrict__ Bpan, int ng, int koff) {
    __shared__ float tt[64][65];
    const int h0 = blockIdx.x * 64;
    const int k0 = blockIdx.y * 64;
    const int tx = threadIdx.x & 63, ty = threadIdx.x >> 6;
    #pragma unroll
    for (int r = ty; r < 64; r += 4)
        tt[r][tx] = src[(int64_t)(k0 + r) * 1024 + h0 + tx];
    __syncthreads();
    for (int it = threadIdx.x; it < 512; it += 256) {
        int hl = it >> 3, kg = it & 7;
        u16x8 hv, lv;
        #pragma unroll
        for (int j = 0; j < 8; j++) {
            float v = tt[kg * 8 + j][hl];
            unsigned short hi = f2bf(v);
            hv[j] = hi;
            lv[j] = f2bf(v - bf2f(hi));
        }
        int np = (h0 + hl) * 4 + ng;
        int64_t a = pan_addr_b(np, koff + k0 + kg * 8);
        *(u16x8*)(Bpan + a) = hv;
        *(u16x8*)(Bpan + a + 1024) = lv;
    }
}

// Row-major [n][k] hi/lo transpose+split for W_h (logits GEMM input).
__global__ __launch_bounds__(256) void k_trans_split(
    const float* __restrict__ src,
    unsigned short* __restrict__ dhi, unsigned short* __restrict__ dlo) {
    __shared__ float tt[64][65];
    const int h0 = blockIdx.x * 64;
    const int k0 = blockIdx.y * 64;
    const int tx = threadIdx.x & 63, ty = threadIdx.x >> 6;
    #pragma unroll
    for (int r = ty; r < 64; r += 4)
        tt[r][tx] = src[(int64_t)(k0 + r) * 1024 + h0 + tx];
    __syncthreads();
    #pragma unroll
    for (int r = ty; r < 64; r += 4) {
        float v = tt[tx][r];
        unsigned short hi = f2bf(v);
        unsigned short lo = f2bf(v - bf2f(hi));
        int64_t o = (int64_t)(h0 + r) * 1024 + k0 + tx;
        dhi[o] = hi;
        dlo[o] = lo;
    }
}

// bias4[n'] = b_g[h], n' = 4h+g
__global__ __launch_bounds__(256) void k_pack_bias(
    const float* __restrict__ bf_, const float* __restrict__ bi_,
    const float* __restrict__ bc_, const float* __restrict__ bo_,
    float* __restrict__ bias4) {
    int n = blockIdx.x * 256 + threadIdx.x;
    if (n < 4096) {
        int g = n & 3, h = n >> 2;
        const float* p = (g == 0) ? bf_ : (g == 1) ? bi_ : (g == 2) ? bc_ : bo_;
        bias4[n] = p[h];
    }
}

// ---------------------------------------------------------------------------
// GATE GEMM: bf16x3, 256x128 tile, BK=32, 8 waves (4M x 2N, 64x64 each),
// 32x32x16 MFMA.  Triple-buffered 144KB LDS, 1 barrier per K-tile.
// Per tile per wave: 16 ds_read_b128 (issued up front) + 3 MFMA clusters
// gated by lgkmcnt(8)/(4)/(0) so the LDS port streams lo-fragments while
// the hh cluster computes.  Stage(t+2) issued mid-tile; vmcnt(6) at exit
// guarantees tile t+1; exit s_barrier protects the triple-buffer rotation.
// ---------------------------------------------------------------------------
#define NT (K1 / 32)   // 64
#define BUFSZ 49152    // A 32KB + B 16KB

__global__ __launch_bounds__(512, 2) void k_gate_gemm(
    const char* __restrict__ Apan, const char* __restrict__ Bpan,
    const float* __restrict__ bias,
    const float* __restrict__ cell,
    float* __restrict__ out0,
    unsigned short* __restrict__ hhi, unsigned short* __restrict__ hlo) {
    extern __shared__ char smem[];  // 3 * 49152

    const int tid  = threadIdx.x;
    const int lane = tid & 63;
    const int w    = tid >> 6;       // 0..7
    const int wm   = w >> 1;         // 0..3 (M)
    const int wn   = w & 1;          // 0..1 (N)
    const int l31  = lane & 31;
    const int lh   = lane >> 5;

    // XCD swizzle: 1024 blocks, 1024%8==0
    const int bid = blockIdx.x;
    const int swz = (bid & 7) * 128 + (bid >> 3);
    const int mp  = swz >> 5;        // 0..31 m-panel (256 rows)
    const int np  = swz & 31;        // 0..31 n-panel (128 cols)
    const int m0  = mp * 256;
    const int n0  = np * 128;

    f32x16 a00 = (f32x16)(0.0f), a01 = (f32x16)(0.0f);
    f32x16 a10 = (f32x16)(0.0f), a11 = (f32x16)(0.0f);

    const char* srcA = Apan + ((int64_t)mp << 21) + w * 1024 + lane * 16;
    const char* srcB = Bpan + ((int64_t)np << 20) + w * 1024 + lane * 16;

    auto STAGE = [&](unsigned dstOff, int t2) {
        const char* sa = srcA + (int64_t)t2 * 32768;
        gload_lds16(sa + 0,     smem + dstOff + 0     + w * 1024);
        gload_lds16(sa + 8192,  smem + dstOff + 8192  + w * 1024);
        gload_lds16(sa + 16384, smem + dstOff + 16384 + w * 1024);
        gload_lds16(sa + 24576, smem + dstOff + 24576 + w * 1024);
        const char* sb = srcB + (int64_t)t2 * 16384;
        gload_lds16(sb + 0,    smem + dstOff + 32768 + w * 1024);
        gload_lds16(sb + 8192, smem + dstOff + 40960 + w * 1024);
    };

    const unsigned ldsBase = lds_off(smem);
    const unsigned aBase = ldsBase + (unsigned)(wm * 8192 + lane * 16);
    const unsigned bBase = ldsBase + 32768u + (unsigned)(wn * 8192 + lane * 16);

    // ---- prologue: stage tiles 0 and 1 ----
    STAGE(0, 0);
    STAGE(BUFSZ, 1);
    asm volatile("s_waitcnt vmcnt(6)" ::: "memory");
    SCHED0();
    __builtin_amdgcn_s_barrier();
    SCHED0();

    unsigned curOff = 0, nxtOff = BUFSZ, stgOff = 2 * BUFSZ;

    #pragma unroll 1
    for (int t = 0; t < NT; ++t) {
        const unsigned aT = aBase + curOff;
        const unsigned bT = bBase + curOff;

        bf16x8 ah00, ah01, ah10, ah11, al00, al01, al10, al11;
        bf16x8 bh00, bh01, bh10, bh11, bl00, bl01, bl10, bl11;

        // issue all 16 reads (order = wait-count order)
        DSR(ah00, aT, 0);
        DSR(ah01, aT, 2048);
        DSR(ah10, aT, 4096);
        DSR(ah11, aT, 6144);
        DSR(bh00, bT, 0);
        DSR(bh01, bT, 2048);
        DSR(bh10, bT, 4096);
        DSR(bh11, bT, 6144);
        DSR(bl00, bT, 1024);
        DSR(bl01, bT, 3072);
        DSR(bl10, bT, 5120);
        DSR(bl11, bT, 7168);
        DSR(al00, aT, 1024);
        DSR(al01, aT, 3072);
        DSR(al10, aT, 5120);
        DSR(al11, aT, 7168);

        if (t < NT - 2) STAGE(stgOff, t + 2);

        // ---- hh cluster (first 8 reads) ----
        SCHED0();
        asm volatile("s_waitcnt lgkmcnt(8)" ::: "memory");
        SCHED0();
        __builtin_amdgcn_s_setprio(1);
        a00 = mfma32(ah00, bh00, a00);
        a01 = mfma32(ah00, bh10, a01);
        a10 = mfma32(ah10, bh00, a10);
        a11 = mfma32(ah10, bh10, a11);
        a00 = mfma32(ah01, bh01, a00);
        a01 = mfma32(ah01, bh11, a01);
        a10 = mfma32(ah11, bh01, a10);
        a11 = mfma32(ah11, bh11, a11);
        __builtin_amdgcn_s_setprio(0);

        // ---- hl cluster (B-lo ready at lgkmcnt(4)) ----
        SCHED0();
        asm volatile("s_waitcnt lgkmcnt(4)" ::: "memory");
        SCHED0();
        __builtin_amdgcn_s_setprio(1);
        a00 = mfma32(ah00, bl00, a00);
        a01 = mfma32(ah00, bl10, a01);
        a10 = mfma32(ah10, bl00, a10);
        a11 = mfma32(ah10, bl10, a11);
        a00 = mfma32(ah01, bl01, a00);
        a01 = mfma32(ah01, bl11, a01);
        a10 = mfma32(ah11, bl01, a10);
        a11 = mfma32(ah11, bl11, a11);
        __builtin_amdgcn_s_setprio(0);

        // ---- lh cluster (A-lo ready at lgkmcnt(0)) ----
        SCHED0();
        asm volatile("s_waitcnt lgkmcnt(0)" ::: "memory");
        SCHED0();
        __builtin_amdgcn_s_setprio(1);
        a00 = mfma32(al00, bh00, a00);
        a01 = mfma32(al00, bh10, a01);
        a10 = mfma32(al10, bh00, a10);
        a11 = mfma32(al10, bh10, a11);
        a00 = mfma32(al01, bh01, a00);
        a01 = mfma32(al01, bh11, a01);
        a10 = mfma32(al11, bh01, a10);
        a11 = mfma32(al11, bh11, a11);
        __builtin_amdgcn_s_setprio(0);

        // ---- tile boundary: counted vmcnt + one barrier ----
        SCHED0();
        if (t < NT - 2) {
            asm volatile("s_waitcnt vmcnt(6)" ::: "memory");
        } else if (t == NT - 2) {
            asm volatile("s_waitcnt vmcnt(0)" ::: "memory");
        }
        if (t < NT - 1) {
            SCHED0();
            __builtin_amdgcn_s_barrier();
            SCHED0();
        }

        unsigned tmp = curOff;
        curOff = nxtOff;
        nxtOff = stgOff;
        stgOff = tmp;
    }

    // ---- fused LSTM epilogue (32x32 C layout: col=lane&31,
    //      row=(r&3)+8*(r>>2)+4*(lane>>5)) ----
    const int lb = lane & ~3;
    const int64_t OFF_H = (int64_t)B_DIM * H_DIM;
    const int64_t OFF_C = (int64_t)2 * B_DIM * H_DIM;
    const int g = lane & 3;
    const int role = lane & 3;

#define EPILOGUE(ACC, MF, NF)                                                \
    {                                                                        \
        int col = n0 + wn * 64 + (NF) * 32 + l31;                            \
        int h = col >> 2;                                                    \
        float bb = bias[col];                                                \
        int rowbase = m0 + wm * 64 + (MF) * 32 + 4 * lh;                     \
        _Pragma("unroll")                                                    \
        for (int r = 0; r < 16; r++) {                                       \
            int row = rowbase + (r & 3) + 8 * (r >> 2);                      \
            float v = ACC[r] + bb;                                           \
            float a = (g == 2) ? tanhf(v) : 1.0f / (1.0f + expf(-v));        \
            float fg = __shfl(a, lb + 0, 64);                                \
            float ig = __shfl(a, lb + 1, 64);                                \
            float ct = __shfl(a, lb + 2, 64);                                \
            float og = __shfl(a, lb + 3, 64);                                \
            int64_t o = (int64_t)row * H_DIM + h;                            \
            float cn = fg * cell[o] + ig * ct;                               \
            float hn = og * tanhf(cn);                                       \
            if (role == 0) {                                                 \
                out0[OFF_C + o] = cn;                                        \
            } else if (role == 1) {                                          \
                out0[OFF_H + o] = hn;                                        \
            } else if (role == 2) {                                          \
                hhi[o] = f2bf(hn);                                           \
            } else {                                                         \
                unsigned short t2 = f2bf(hn);                                \
                hlo[o] = f2bf(hn - bf2f(t2));                                \
            }                                                                \
        }                                                                    \
    }

    EPILOGUE(a00, 0, 0);
    EPILOGUE(a01, 0, 1);
    EPILOGUE(a10, 1, 0);
    EPILOGUE(a11, 1, 1);
#undef EPILOGUE
}

// ---------------------------------------------------------------------------
// LOGITS GEMM: bf16x3, 128x128 tile, BK=32, 4 waves (m97 structure).
// ---------------------------------------------------------------------------
__global__ __launch_bounds__(256, 2) void k_gemm128(
    const unsigned short* __restrict__ Ahi, const unsigned short* __restrict__ Alo,
    const unsigned short* __restrict__ Bhi, const unsigned short* __restrict__ Blo,
    int K, int Ncols,
    const float* __restrict__ bias,
    float* __restrict__ out0) {
    __shared__ char smem[32768];

    const int tid  = threadIdx.x;
    const int lane = tid & 63;
    const int w    = tid >> 6;
    const int wr   = (w >> 1) * 64;
    const int wc   = (w & 1) * 64;
    const int m0   = blockIdx.y * 128;
    const int n0   = blockIdx.x * 128;

    f32x4 acc[4][4];
    #pragma unroll
    for (int i = 0; i < 4; i++)
        #pragma unroll
        for (int j = 0; j < 4; j++) acc[i][j] = (f32x4){0.f, 0.f, 0.f, 0.f};

    const int sr = tid >> 3;
    const int s2 = (tid & 7) ^ (sr & 7);
    const unsigned short* Asrc =
        ((s2 < 4) ? Ahi : Alo) + (int64_t)(m0 + sr) * K + (s2 & 3) * 8;
    const unsigned short* Bsrc =
        ((s2 < 4) ? Bhi : Blo) + (int64_t)(n0 + sr) * K + (s2 & 3) * 8;

    const int q  = lane >> 4;
    const int fr = lane & 15;
    const int sw = lane & 7;
    const int hiSlot = (q ^ sw) << 4;
    const int loSlot = ((q + 4) ^ sw) << 4;

    for (int kt = 0; kt < K; kt += 32) {
        __syncthreads();
        #pragma unroll
        for (int i = 0; i < 4; i++) {
            gload_lds16(Asrc + (int64_t)i * 32 * K + kt, smem + i * 4096 + w * 1024);
            gload_lds16(Bsrc + (int64_t)i * 32 * K + kt, smem + 16384 + i * 4096 + w * 1024);
        }
        __syncthreads();

        bf16x8 ah[4], al[4], bh[4], bl[4];
        #pragma unroll
        for (int mi = 0; mi < 4; mi++) {
            const char* rp = smem + (wr + mi * 16 + fr) * 128;
            ah[mi] = *(const bf16x8*)(rp + hiSlot);
            al[mi] = *(const bf16x8*)(rp + loSlot);
        }
        #pragma unroll
        for (int ni = 0; ni < 4; ni++) {
            const char* rp = smem + 16384 + (wc + ni * 16 + fr) * 128;
            bh[ni] = *(const bf16x8*)(rp + hiSlot);
            bl[ni] = *(const bf16x8*)(rp + loSlot);
        }
        #pragma unroll
        for (int mi = 0; mi < 4; mi++)
            #pragma unroll
            for (int ni = 0; ni < 4; ni++) {
                acc[mi][ni] = mfma16(ah[mi], bh[ni], acc[mi][ni]);
                acc[mi][ni] = mfma16(ah[mi], bl[ni], acc[mi][ni]);
                acc[mi][ni] = mfma16(al[mi], bh[ni], acc[mi][ni]);
            }
    }

    #pragma unroll
    for (int mi = 0; mi < 4; mi++)
        #pragma unroll
        for (int ni = 0; ni < 4; ni++) {
            int col = n0 + wc + ni * 16 + fr;
            int rowb = m0 + wr + mi * 16 + q * 4;
            float bb = bias[col];
            #pragma unroll
            for (int j = 0; j < 4; j++)
                out0[(int64_t)(rowb + j) * Ncols + col] = acc[mi][ni][j] + bb;
        }
}

// ---------------------------------------------------------------------------
// Row-wise log_softmax over [8192][1024]: one block per row.
// ---------------------------------------------------------------------------
__global__ __launch_bounds__(256) void k_logsoftmax(
    const float* __restrict__ logits, float* __restrict__ out) {
    const int row = blockIdx.x;
    const int t = threadIdx.x;
    const float* x = logits + (int64_t)row * 1024;
    float4 v = *(const float4*)(x + t * 4);

    float m = fmaxf(fmaxf(v.x, v.y), fmaxf(v.z, v.w));
    #pragma unroll
    for (int off = 1; off < 64; off <<= 1) m = fmaxf(m, __shfl_xor(m, off, 64));
    __shared__ float sm[4];
    __shared__ float ssum[4];
    int ln = t & 63, wv = t >> 6;
    if (ln == 0) sm[wv] = m;
    __syncthreads();
    m = fmaxf(fmaxf(sm[0], sm[1]), fmaxf(sm[2], sm[3]));

    float s = expf(v.x - m) + expf(v.y - m) + expf(v.z - m) + expf(v.w - m);
    #pragma unroll
    for (int off = 1; off < 64; off <<= 1) s += __shfl_xor(s, off, 64);
    if (ln == 0) ssum[wv] = s;
    __syncthreads();
    s = ssum[0] + ssum[1] + ssum[2] + ssum[3];

    float lse = m + logf(s);
    float4 o;
    o.x = v.x - lse; o.y = v.y - lse; o.z = v.z - lse; o.w = v.w - lse;
    *(float4*)(out + (int64_t)row * 1024 + t * 4) = o;
}

// ---------------------------------------------------------------------------
extern "C" void kernel_launch(void* const* d_in, const int* in_sizes, int n_in,
                              void* d_out, int out_size, void* d_ws, size_t ws_size,
                              hipStream_t stream) {
    const float* input  = (const float*)d_in[0];
    const float* hidden = (const float*)d_in[1];
    const float* cell   = (const float*)d_in[2];
    const float* W_f = (const float*)d_in[3];
    const float* U_f = (const float*)d_in[4];
    const float* b_f = (const float*)d_in[5];
    const float* W_i = (const float*)d_in[6];
    const float* U_i = (const float*)d_in[7];
    const float* b_i = (const float*)d_in[8];
    const float* W_c = (const float*)d_in[9];
    const float* U_c = (const float*)d_in[10];
    const float* b_c = (const float*)d_in[11];
    const float* W_o = (const float*)d_in[12];
    const float* U_o = (const float*)d_in[13];
    const float* b_o = (const float*)d_in[14];
    const float* W_h = (const float*)d_in[15];
    const float* b_h = (const float*)d_in[16];
    float* out = (float*)d_out;

    char* ws = (char*)d_ws;
    char*           Apan = ws;                                  // 64 MB
    char*           Bpan = ws + 67108864;                       // 32 MB
    unsigned short* hhi  = (unsigned short*)(ws + 100663296);   // 16 MB
    unsigned short* hlo  = (unsigned short*)(ws + 117440512);   // 16 MB
    unsigned short* whhi = (unsigned short*)(ws + 134217728);   // 2 MB
    unsigned short* whlo = (unsigned short*)(ws + 136314880);   // 2 MB
    float*          bias4 = (float*)(ws + 138412032);           // 16 KB
    float*          logits = (float*)(ws);                      // aliases Apan
    if (ws_size < (size_t)138428416) return;

    hipFuncSetAttribute((const void*)k_gate_gemm,
                        hipFuncAttributeMaxDynamicSharedMemorySize, 3 * BUFSZ);

    k_pack_x<<<2048, 256, 0, stream>>>(input, hidden, Apan);

    const float* Warr[8] = {W_f, W_i, W_c, W_o, U_f, U_i, U_c, U_o};
    for (int a = 0; a < 8; a++)
        k_trans_split_pan<<<dim3(16, 16), 256, 0, stream>>>(
            Warr[a], Bpan, a & 3, (a >> 2) * 1024);
    k_trans_split<<<dim3(16, 16), 256, 0, stream>>>(W_h, whhi, whlo);
    k_pack_bias<<<16, 256, 0, stream>>>(b_f, b_i, b_c, b_o, bias4);

    // gates GEMM + fused LSTM epilogue: M=8192, N'=4096, K=2048, 1024 blocks
    k_gate_gemm<<<1024, 512, 3 * BUFSZ, stream>>>(
        Apan, Bpan, bias4, cell, out, hhi, hlo);

    // logits GEMM: M=8192, N=1024, K=1024
    k_gemm128<<<dim3(8, 64), 256, 0, stream>>>(
        hhi, hlo, whhi, whlo, 1024, 1024, b_h, logits);

    k_logsoftmax<<<8192, 256, 0, stream>>>(logits, out);
}